// Round 8
// baseline (67.012 us; speedup 1.0000x reference)
//
#include <hip/hip_runtime.h>

// Conv2d 5x5, C=3, O=1, stride 1, pad 2, N=256, H=W=224, +bias.
// R8: low-VGPR / high-TLP walker.
//   R7 post-mortem: TXv=4 cut VALU to ~24us but full-unroll hoisting drove
//   VGPR to 128 -> ~2 waves/SIMD -> stalls still dominate (55.5us vs ~30 floor).
//   Occupancy ladder (measured): waves/SIMD halve at VGPR 64/128 -> only
//   <=64 unlocks 8 waves/SIMD. Strategy flip: serial-per-wave, saturate by TLP.
// Changes:
//   - slim window loads: float2(x0-2) + float4(x0) + float2(x0+4) per channel
//     = exactly the 8 window floats; no double-buffer (24 load regs live).
//   - __builtin_amdgcn_sched_barrier(0) between steps: stops cross-step load
//     hoisting -> live set ~55 VGPR (target <=64).
//   - SY=4 (NSTRIP=56): acc=16 regs; grid 3136 blocks = 12.25/CU, supplies
//     the 8 resident blocks/CU needed at 8 waves/SIMD.
//   - boundary row guards only s in {0,1,6,7}; edge lanes redirect masked
//     loads inward (zeroed in window) -> zero OOB.
//   - NO launch_bounds min-waves arg (R2/R3: forced VGPR=40 -> mega-spill).

namespace {

constexpr int Hc = 224, Wc = 224, Cc = 3;
constexpr int HW = Hc * Wc;
constexpr int CHW = Cc * HW;
constexpr int TXv = 4;              // outputs per thread in x (float4)
constexpr int NCOL = Wc / TXv;      // 56
constexpr int SY = 4;               // strip height per thread
constexpr int NSTRIP = Hc / SY;     // 56
constexpr int BLK = 256;
constexpr int NSTEP = SY + 4;       // 8 input rows per strip

__global__ __launch_bounds__(BLK) void conv5x5_r8(
    const float* __restrict__ x, const float* __restrict__ wl,
    const float* __restrict__ bptr, float* __restrict__ out) {
  const int t = blockIdx.x * BLK + threadIdx.x;
  // decode: col fastest (coalescing), then strip, then n
  const int col = t % NCOL;
  const int rest = t / NCOL;
  const int strip = rest % NSTRIP;
  const int n = rest / NSTRIP;

  const int x0 = col * TXv;
  const int y0 = strip * SY;
  const bool lo = (col == 0);          // left image edge lane
  const bool hi = (col == NCOL - 1);   // right image edge lane

  // Weights: wave-uniform, compile-time offsets -> s_load (SGPRs).
  float w[Cc][5][5];
#pragma unroll
  for (int c = 0; c < Cc; ++c)
#pragma unroll
    for (int i = 0; i < 25; ++i) w[c][i / 5][i % 5] = wl[c * 25 + i];
  const float bias = bptr[0];

  const float* xb = x + (size_t)n * CHW + x0;
  float* ob = out + (size_t)n * HW + x0;

  // Window floats needed: [x0-2, x0+5]. Loads: f2 @ x0-2 (8B-aligned since
  // x0%4==0), f4 @ x0 (16B), f2 @ x0+4 (8B). Edge lanes redirect the masked
  // load inward (values zeroed in window build) -> zero OOB accesses.
  const int dL = lo ? 0 : -2;
  const int dR = hi ? 0 : 4;

  float4 acc[SY];                      // statically indexed
#pragma unroll
  for (int o = 0; o < SY; ++o) acc[o] = make_float4(0.f, 0.f, 0.f, 0.f);

  // Input row s (yi = y0-2+s) feeds output rows o = s-ky, ky in [0,4].
  // acc[o]: born s=o, stored s=o+4. All indices compile-time after unroll.
#pragma unroll
  for (int s = 0; s < NSTEP; ++s) {
    const int yi = y0 + s - 2;
    // Middle steps s in [2, SY+1]: 0 <= yi <= y0+SY-1 <= 223 always.
    const bool boundary = (s < 2) || (s >= SY + 2);

    bool rv = true;
    int yc = yi;
    if (boundary) {
      rv = (yi >= 0) && (yi < Hc);
      yc = yi < 0 ? 0 : (yi >= Hc ? Hc - 1 : yi);     // clamp address
    }

    // Issue this step's 9 slim loads up front (batched).
    float2 Lh[Cc]; float4 Mv[Cc]; float2 Rh[Cc];
#pragma unroll
    for (int c = 0; c < Cc; ++c) {
      const float* pc = xb + (size_t)c * HW + (size_t)yc * Wc;
      Lh[c] = *(const float2*)(pc + dL);
      Mv[c] = *(const float4*)(pc);
      Rh[c] = *(const float2*)(pc + dR);
    }

#pragma unroll
    for (int c = 0; c < Cc; ++c) {
      const bool z = boundary && !rv;       // whole-row zero (pad in y)
      float win[8];                          // win[j] = x[x0-2+j]
      win[0] = (z || lo) ? 0.f : Lh[c].x;
      win[1] = (z || lo) ? 0.f : Lh[c].y;
      win[2] = z ? 0.f : Mv[c].x;
      win[3] = z ? 0.f : Mv[c].y;
      win[4] = z ? 0.f : Mv[c].z;
      win[5] = z ? 0.f : Mv[c].w;
      win[6] = (z || hi) ? 0.f : Rh[c].x;
      win[7] = (z || hi) ? 0.f : Rh[c].y;
#pragma unroll
      for (int ky = 0; ky < 5; ++ky) {
        const int o = s - ky;
        if (o < 0 || o >= SY) continue;               // compile-time
#pragma unroll
        for (int kx = 0; kx < 5; ++kx) {
          const float wv = w[c][ky][kx];
          acc[o].x = fmaf(win[kx + 0], wv, acc[o].x);
          acc[o].y = fmaf(win[kx + 1], wv, acc[o].y);
          acc[o].z = fmaf(win[kx + 2], wv, acc[o].z);
          acc[o].w = fmaf(win[kx + 3], wv, acc[o].w);
        }
      }
    }

    if (s >= 4) {                     // output row s-4 complete
      float4 oo;
      oo.x = acc[s - 4].x + bias;
      oo.y = acc[s - 4].y + bias;
      oo.z = acc[s - 4].z + bias;
      oo.w = acc[s - 4].w + bias;
      *(float4*)(ob + (size_t)(y0 + s - 4) * Wc) = oo;
    }

    // Fence: no cross-step scheduling -> one-step load depth -> VGPR <= ~60.
    __builtin_amdgcn_sched_barrier(0);
  }
}

}  // namespace

extern "C" void kernel_launch(void* const* d_in, const int* in_sizes, int n_in,
                              void* d_out, int out_size, void* d_ws, size_t ws_size,
                              hipStream_t stream) {
  const float* x  = (const float*)d_in[0];   // [N,3,224,224] f32
  const float* wl = (const float*)d_in[1];   // [1,75] f32
  const float* b  = (const float*)d_in[2];   // [1] f32
  float* out = (float*)d_out;                // [N,224,224] f32

  const int N = out_size / HW;               // 256
  const int total = N * NSTRIP * NCOL;       // 802816
  const int nblk = total / BLK;              // 3136 blocks = 12.25 per CU

  conv5x5_r8<<<nblk, BLK, 0, stream>>>(x, wl, b, out);
}